// Round 8
// baseline (423.840 us; speedup 1.0000x reference)
//
#include <hip/hip_runtime.h>
#include <cstdint>

#define DEVINL __device__ __forceinline__

// ---------------- problem geometry ----------------
constexpr int NB = 8;        // batch
constexpr int NG = 50;       // gts per image
constexpr int KTOT = 120087; // total anchors per image
constexpr int BK = NB * KTOT;

constexpr int L_W[5]   = {100, 50, 25, 13, 7};
constexpr int L_K[5]   = {90000, 22500, 5625, 1521, 441};
constexpr int L_OFF[5] = {0, 90000, 112500, 118125, 119646};
constexpr int L_WSB[5] = {0, 720000, 900000, 945000, 957168}; // L_OFF * NB

// base anchor tables (float64, matching numpy bit-for-bit)
constexpr double HR_T[3] = {0.7071067811865476, 1.0, 1.4142135623730951}; // sqrt(ratios)
constexpr double WR_T[3] = {1.0 / HR_T[0], 1.0, 1.0 / HR_T[2]};          // 1/sqrt(ratios)
constexpr double SC_T[3] = {4.0, 5.039684199579493, 6.3496042078727974}; // 4*2^(i/3)

// ---------------- device-global scratch ----------------
__device__ float4 g_anc[KTOT];
__device__ double g_accs[256][2];
__device__ unsigned g_ns;
__device__ unsigned g_done;
__device__ unsigned g_gtmax[NB * NG];
__device__ int8_t g_lab[BK];
__device__ __align__(8) int8_t g_lw[BK];
__device__ int8_t g_pos[BK];
__device__ int8_t g_mg[BK];

// ---------------- helpers ----------------
DEVINL unsigned encf(float f) { // monotonic, equality-preserving float->uint
  unsigned u = __float_as_uint(f);
  return (u & 0x80000000u) ? ~u : (u | 0x80000000u);
}
DEVINL int lvl_of(int k) {
  return (k < 90000) ? 0 : (k < 112500) ? 1 : (k < 118125) ? 2 : (k < 119646) ? 3 : 4;
}
// the ONLY IoU expression — identical instruction sequence everywhere
DEVINL float iou_one(float ax0, float ay0, float ax1, float ay1, float areaA,
                     float bx0, float by0, float bx1, float by1, float areaB) {
  float ltx = fmaxf(ax0, bx0);
  float lty = fmaxf(ay0, by0);
  float rbx = fminf(ax1, bx1);
  float rby = fminf(ay1, by1);
  float wx = fmaxf(rbx - ltx, 0.0f);
  float wy = fmaxf(rby - lty, 0.0f);
  float inter = wx * wy;
  return __fdividef(inter, areaA + areaB - inter);
}

// shared f64 anchor math: the ONE expression tree producing anchor f32 coords
DEVINL void wh_f64(int l, int a, double& wsz, double& hsz) {
  int st = 8 << l;
  int ridx = a / 3, sidx = a - ridx * 3;
  double sc = (sidx == 0) ? SC_T[0] : (sidx == 1) ? SC_T[1] : SC_T[2];
  double wr = (ridx == 0) ? WR_T[0] : (ridx == 1) ? WR_T[1] : WR_T[2];
  double hr = (ridx == 0) ? HR_T[0] : (ridx == 1) ? HR_T[1] : HR_T[2];
  wsz = wr * sc * (double)st;
  hsz = hr * sc * (double)st;
}
DEVINL void anchor_from_wh(int l, int xi, int yi, double wsz, double hsz,
                           float& x0, float& y0, float& x1, float& y1) {
  int st = 8 << l;
  double cx = (double)(xi * st), cy = (double)(yi * st);
  x0 = (float)(cx - wsz * 0.5);
  y0 = (float)(cy - hsz * 0.5);
  x1 = (float)(cx + wsz * 0.5);
  y1 = (float)(cy + hsz * 0.5);
}

// ---------------- kernel 0: setup + analytic gt_max (fused, independent) ----
constexpr int NBLK_ANC = (KTOT + 255) / 256; // 470

DEVINL int axis_cand(int xi, int i0, int lo, int hi, int Wm1) {
  int c;
  if (xi < 4) c = i0 - 1 + xi;
  else if (xi == 4) c = lo;
  else if (xi == 5) c = lo + 1;
  else if (xi == 6) c = hi - 1;
  else if (xi == 7) c = hi;
  else if (xi == 8) c = 0;
  else c = Wm1;
  return min(max(c, 0), Wm1);
}

__global__ __launch_bounds__(256) void k_setup(const float* __restrict__ tb) {
  if (blockIdx.x < NBLK_ANC) {
    if (blockIdx.x == 0) {
      int t = threadIdx.x;
      g_accs[t][0] = 0.0;
      g_accs[t][1] = 0.0;
      if (t == 0) { g_ns = 0u; g_done = 0u; }
    }
    int k = blockIdx.x * 256 + threadIdx.x;
    if (k >= KTOT) return;
    int l = lvl_of(k);
    int r = k - L_OFF[l];
    int loc = r / 9;
    int a = r - loc * 9;
    int W = L_W[l];
    int y = loc / W;
    int x = loc - y * W;
    double wsz, hsz;
    wh_f64(l, a, wsz, hsz);
    float x0, y0, x1, y1;
    anchor_from_wh(l, x, y, wsz, hsz, x0, y0, x1, y1);
    g_anc[k] = make_float4(x0, y0, x1, y1);
    return;
  }
  // ---- analytic gtmax: candidates recompute anchors with the SAME f64
  // expression (bit-equal to g_anc) and use the SAME iou_one -> max is
  // bit-identical to brute force over all anchors.
  const int bg = blockIdx.x - NBLK_ANC; // b*NG + g
  float4 v = reinterpret_cast<const float4*>(tb)[bg];
  const float bx0 = v.x, by0 = v.y, bx1 = v.z, by1 = v.w;
  const float areaB = (bx1 - bx0) * (by1 - by0);
  const float bcx = 0.5f * (bx0 + bx1), bcy = 0.5f * (by0 + by1);

  float m = -1.0f;
  for (int t = threadIdx.x; t < 4500; t += 256) {
    int l = t / 900;
    int rem = t - l * 900;
    int a = rem / 100;
    int rem2 = rem - a * 100;
    int xi = rem2 / 10;
    int yi = rem2 - xi * 10;
    int W = (l == 0) ? 100 : (l == 1) ? 50 : (l == 2) ? 25 : (l == 3) ? 13 : 7;
    float stf = (float)(8 << l);
    double wsz, hsz;
    wh_f64(l, a, wsz, hsz);
    float whalf = (float)(wsz * 0.5);
    float hhalf = (float)(hsz * 0.5);
    int i0x = (int)floorf(bcx / stf);
    int lox = (int)ceilf(whalf / stf);
    int hix = (int)floorf((800.0f - whalf) / stf);
    int i0y = (int)floorf(bcy / stf);
    int loy = (int)ceilf(hhalf / stf);
    int hiy = (int)floorf((800.0f - hhalf) / stf);
    int cx = axis_cand(xi, i0x, lox, hix, W - 1);
    int cy = axis_cand(yi, i0y, loy, hiy, W - 1);
    float ax0, ay0, ax1, ay1;
    anchor_from_wh(l, cx, cy, wsz, hsz, ax0, ay0, ax1, ay1);
    bool inside = (ax0 >= 0.0f) & (ay0 >= 0.0f) & (ax1 <= 800.0f) & (ay1 <= 800.0f);
    float areaA = (ax1 - ax0) * (ay1 - ay0);
    float iou = inside ? iou_one(ax0, ay0, ax1, ay1, areaA,
                                 bx0, by0, bx1, by1, areaB)
                       : -1.0f;
    m = fmaxf(m, iou);
  }
#pragma unroll
  for (int off = 32; off; off >>= 1) m = fmaxf(m, __shfl_down(m, off));
  __shared__ float s_m[4];
  int lane = threadIdx.x & 63, wid = threadIdx.x >> 6;
  if (lane == 0) s_m[wid] = m;
  __syncthreads();
  if (threadIdx.x == 0) {
    float r = fmaxf(fmaxf(s_m[0], s_m[1]), fmaxf(s_m[2], s_m[3]));
    g_gtmax[bg] = encf(r); // sole writer, no atomic
  }
}

// ---------------- kernel 1: assignment, ballot-compacted gt list ------------
constexpr int APB = 4;
__global__ __launch_bounds__(256) void k_assign(const float* __restrict__ tb,
                                                const int* __restrict__ tcls) {
  const int b = blockIdx.y;
  __shared__ float s_b[NG][8]; // x0,y0,x1,y1,area,qmax
  __shared__ int s_cls[NG];
  __shared__ unsigned s_cnt;
  int tid = threadIdx.x;
  if (tid == 0) s_cnt = 0u;
  if (tid < NG) {
    float4 v = reinterpret_cast<const float4*>(tb)[b * NG + tid];
    s_b[tid][0] = v.x; s_b[tid][1] = v.y; s_b[tid][2] = v.z; s_b[tid][3] = v.w;
    s_b[tid][4] = (v.z - v.x) * (v.w - v.y);
    unsigned gm = g_gtmax[b * NG + tid];
    s_b[tid][5] = (gm > 0x80000000u) ? __uint_as_float(gm ^ 0x80000000u)
                                     : __uint_as_float(0x7FC00000u); // NaN: never ==
    s_cls[tid] = tcls[b * NG + tid];
  }
  __syncthreads();

  const int base = (blockIdx.x * 256 + tid) * APB;
  float Ax0[APB], Ay0[APB], Ax1[APB], Ay1[APB], areaA[APB];
  bool inside[APB];
  float ex0 = __builtin_inff(), ey0 = __builtin_inff();
  float ex1 = -__builtin_inff(), ey1 = -__builtin_inff();
#pragma unroll
  for (int ap = 0; ap < APB; ++ap) {
    int k = base + ap;
    bool valid = k < KTOT;
    float4 A = g_anc[valid ? k : 0];
    bool ins = valid & (A.x >= 0.0f) & (A.y >= 0.0f) & (A.z <= 800.0f) & (A.w <= 800.0f);
    inside[ap] = ins;
    ex0 = fminf(ex0, ins ? A.x : __builtin_inff());
    ey0 = fminf(ey0, ins ? A.y : __builtin_inff());
    ex1 = fmaxf(ex1, ins ? A.z : -__builtin_inff());
    ey1 = fmaxf(ey1, ins ? A.w : -__builtin_inff());
    if (!ins) A = make_float4(-4000.0f, -4000.0f, -3999.0f, -3999.0f); // IoU==0 vs any gt
    Ax0[ap] = A.x; Ay0[ap] = A.y; Ax1[ap] = A.z; Ay1[ap] = A.w;
    areaA[ap] = (A.z - A.x) * (A.w - A.y);
  }
#pragma unroll
  for (int off = 1; off < 64; off <<= 1) {
    ex0 = fminf(ex0, __shfl_xor(ex0, off));
    ey0 = fminf(ey0, __shfl_xor(ey0, off));
    ex1 = fmaxf(ex1, __shfl_xor(ex1, off));
    ey1 = fmaxf(ey1, __shfl_xor(ey1, off));
  }
  unsigned long long amask;
  {
    int g = tid & 63;
    bool act = false;
    if (g < NG) {
      float ox = fminf(ex1, s_b[g][2]) - fmaxf(ex0, s_b[g][0]);
      float oy = fminf(ey1, s_b[g][3]) - fmaxf(ey0, s_b[g][1]);
      act = (ox > 0.0f) && (oy > 0.0f);
    }
    amask = __ballot(act);
  }

  float best[APB];
  int arg[APB], lqg[APB];
#pragma unroll
  for (int ap = 0; ap < APB; ++ap) { best[ap] = -2.0f; arg[ap] = 0; lqg[ap] = -1; }

  while (amask) { // ascending g preserves first-max / last-g semantics
    int g = __builtin_ctzll(amask);
    amask &= amask - 1;
    float gx0 = s_b[g][0], gy0 = s_b[g][1], gx1 = s_b[g][2], gy1 = s_b[g][3];
    float gar = s_b[g][4], qmx = s_b[g][5];
#pragma unroll
    for (int ap = 0; ap < APB; ++ap) {
      float iou = iou_one(Ax0[ap], Ay0[ap], Ax1[ap], Ay1[ap], areaA[ap],
                          gx0, gy0, gx1, gy1, gar);
      if (iou > best[ap]) { best[ap] = iou; arg[ap] = g; }
      if (iou == qmx) lqg[ap] = g;
    }
  }

  int cnt = 0;
#pragma unroll
  for (int ap = 0; ap < APB; ++ap) {
    int k = base + ap;
    if (k < KTOT) {
      int lab = (best[ap] >= 0.5f) ? 1 : ((best[ap] >= 0.4f) ? -1 : 0);
      int mg = arg[ap];
      if (lqg[ap] >= 0) { lab = 1; mg = lqg[ap]; }
      bool pos = (lab == 1) && inside[ap];
      bool neg = (lab == 0) && inside[ap];
      int l = lvl_of(k);
      int r = k - L_OFF[l];
      int widx = L_WSB[l] + b * L_K[l] + r;
      g_lab[widx] = pos ? (int8_t)s_cls[mg] : (int8_t)0;
      g_lw[widx] = (pos || neg) ? 1 : 0;
      g_pos[widx] = pos ? 1 : 0;
      g_mg[widx] = (int8_t)mg;
      cnt += (pos || neg) ? 1 : 0;
    }
  }
#pragma unroll
  for (int off = 32; off; off >>= 1) cnt += __shfl_down(cnt, off);
  if ((tid & 63) == 0 && cnt) atomicAdd(&s_cnt, (unsigned)cnt);
  __syncthreads();
  if (tid == 0 && s_cnt) atomicAdd(&g_ns, s_cnt);
}

// ---------------- kernel 2: loss (3-part grid) + fused finalize -------------
// Part V (levels 0,1; HW%4==0): thread = one float4 of one channel row.
// Part S (levels 2-4; odd HW, float4 misaligned): element-per-thread.
// Part B: thread = 4 consecutive anchor-slots, bbox only (pos-gated).
constexpr int VT0 = 1440000;               // L0 vec threads (8*72*2500)
constexpr int VT1 = 360000;                // L1 vec threads (8*72*625)
constexpr int V_TOT = VT0 + VT1;           // 1,800,000
constexpr int ST2 = 360000, ST3 = 97344, ST4 = 28224; // scalar elements L2-4
constexpr int S_TOT = ST2 + ST3 + ST4;     // 485,568
constexpr int BT0 = 180000, BT1 = 45000, BT2 = 11256, BT3 = 3048, BT4 = 888;
constexpr int B_TOT = BT0 + BT1 + BT2 + BT3 + BT4; // 240,192
constexpr int LOSS_THREADS = V_TOT + S_TOT + B_TOT; // 2,525,760
constexpr int LOSS_BLOCKS = (LOSS_THREADS + 255) / 256;

DEVINL float bce_one(float x, int lab, int c) {
  float t = (lab == c) ? 1.0f : 0.0f;
  float ax = fabsf(x);
  float ex = __expf(-ax);
  return fmaxf(x, 0.0f) - x * t + __logf(1.0f + ex);
}

template <int HW, int KL, int WSB>
DEVINL void cls_vec(const float* __restrict__ cls, int j, float& vc) {
  constexpr int GPL = HW / 4;
  constexpr int NPG = 72 * GPL;
  int b = j / NPG;
  int rem = j - b * NPG;
  int ch = rem / GPL;
  int gi = rem - ch * GPL;
  int a = ch >> 3, c = ch & 7;
  int pix0 = gi * 4;
  float4 v4 = *reinterpret_cast<const float4*>(cls + (b * 72 + ch) * HW + pix0);
  float xs[4] = {v4.x, v4.y, v4.z, v4.w};
  int qb = pix0 * 9 + a;
  int ib = WSB + b * KL + qb;
#pragma unroll
  for (int e = 0; e < 4; ++e) {
    float w = (float)g_lw[WSB + 8 * (qb + 9 * e) + c];
    if (w != 0.0f) {
      int lab = g_lab[ib + 9 * e];
      vc += bce_one(xs[e], lab, c);
    }
  }
}

template <int HW, int KL, int WSB>
DEVINL void cls_scalar(const float* __restrict__ cls, int j, float& vc) {
  constexpr int NPE = 72 * HW;
  int b = j / NPE;
  int rem = j - b * NPE;
  int ch = rem / HW;
  int pix = rem - ch * HW;
  int a = ch >> 3, c = ch & 7;
  int q = pix * 9 + a;
  float w = (float)g_lw[WSB + 8 * q + c];
  if (w != 0.0f) {
    float x = cls[(b * 72 + ch) * HW + pix];
    int lab = g_lab[WSB + b * KL + q];
    vc += bce_one(x, lab, c);
  }
}

template <int HW, int KL, int WSB, int LOFF, int GRP>
DEVINL void box_grp(const float* __restrict__ reg, const float4* __restrict__ tb4,
                    int j, float& vb) {
  int b = j / GRP;
  int gi = j - b * GRP;
  int q0 = gi * 4;
  int nval = (q0 + 4 <= KL) ? 4 : (KL - q0);
#pragma unroll
  for (int e = 0; e < 4; ++e) {
    if (e < nval && g_pos[WSB + b * KL + q0 + e]) {
      int q = q0 + e;
      int mg = g_mg[WSB + b * KL + q];
      int pix = q / 9;
      int a = q - pix * 9;
      float4 A = g_anc[LOFF + q];
      float aw = A.z - A.x, ah = A.w - A.y;
      float acx = A.x + 0.5f * aw, acy = A.y + 0.5f * ah;
      float4 gb = tb4[b * NG + mg];
      float gw = gb.z - gb.x, gh = gb.w - gb.y;
      float gcx = gb.x + 0.5f * gw, gcy = gb.y + 0.5f * gh;
      const float* rbase = reg + (b * 36 + a * 4) * HW + pix;
      vb += fabsf(rbase[0] - (gcx - acx) / aw);
      vb += fabsf(rbase[HW] - (gcy - acy) / ah);
      vb += fabsf(rbase[2 * HW] - logf(gw / aw));
      vb += fabsf(rbase[3 * HW] - logf(gh / ah));
    }
  }
}

__global__ __launch_bounds__(256) void k_loss(
    const float* __restrict__ c0, const float* __restrict__ c1,
    const float* __restrict__ c2, const float* __restrict__ c3,
    const float* __restrict__ c4, const float* __restrict__ r0,
    const float* __restrict__ r1, const float* __restrict__ r2,
    const float* __restrict__ r3, const float* __restrict__ r4,
    const float* __restrict__ tb, float* __restrict__ out) {
  const float4* tb4 = reinterpret_cast<const float4*>(tb);
  int T = blockIdx.x * 256 + threadIdx.x;
  float vc = 0.0f, vb = 0.0f;
  if (T < VT0) {
    cls_vec<10000, 90000, 0>(c0, T, vc);
  } else if (T < V_TOT) {
    cls_vec<2500, 22500, 720000>(c1, T - VT0, vc);
  } else if (T < V_TOT + S_TOT) {
    int t2 = T - V_TOT;
    if (t2 < ST2)            cls_scalar<625, 5625, 900000>(c2, t2, vc);
    else if (t2 < ST2 + ST3) cls_scalar<169, 1521, 945000>(c3, t2 - ST2, vc);
    else                     cls_scalar<49, 441, 957168>(c4, t2 - ST2 - ST3, vc);
  } else if (T < LOSS_THREADS) {
    int t3 = T - V_TOT - S_TOT;
    if (t3 < BT0)                        box_grp<10000, 90000, 0, 0, 22500>(r0, tb4, t3, vb);
    else if (t3 < BT0 + BT1)             box_grp<2500, 22500, 720000, 90000, 5625>(r1, tb4, t3 - BT0, vb);
    else if (t3 < BT0 + BT1 + BT2)       box_grp<625, 5625, 900000, 112500, 1407>(r2, tb4, t3 - BT0 - BT1, vb);
    else if (t3 < BT0 + BT1 + BT2 + BT3) box_grp<169, 1521, 945000, 118125, 381>(r3, tb4, t3 - BT0 - BT1 - BT2, vb);
    else                                 box_grp<49, 441, 957168, 119646, 111>(r4, tb4, t3 - BT0 - BT1 - BT2 - BT3, vb);
  }
#pragma unroll
  for (int off = 32; off; off >>= 1) {
    vc += __shfl_down(vc, off);
    vb += __shfl_down(vb, off);
  }
  __shared__ float sc_[4], sb_[4];
  __shared__ bool s_last;
  int lane = threadIdx.x & 63;
  int wid = threadIdx.x >> 6;
  if (lane == 0) { sc_[wid] = vc; sb_[wid] = vb; }
  __syncthreads();
  if (threadIdx.x == 0) {
    float tc = sc_[0] + sc_[1] + sc_[2] + sc_[3];
    float tbx = sb_[0] + sb_[1] + sb_[2] + sb_[3];
    int slot = blockIdx.x & 255;
    if (tc != 0.0f) atomicAdd(&g_accs[slot][0], (double)tc);
    if (tbx != 0.0f) atomicAdd(&g_accs[slot][1], (double)tbx);
    __threadfence();
    unsigned old = atomicAdd(&g_done, 1u);
    s_last = (old == gridDim.x - 1);
  }
  __syncthreads();
  if (s_last) { // last block reduces the 256 slots and writes outputs
    int t = threadIdx.x;
    double a0 = atomicAdd(&g_accs[t][0], 0.0); // atomic read -> coherent
    double a1 = atomicAdd(&g_accs[t][1], 0.0);
#pragma unroll
    for (int off = 32; off; off >>= 1) {
      a0 += __shfl_down(a0, off);
      a1 += __shfl_down(a1, off);
    }
    __shared__ double s0[4], s1[4];
    if (lane == 0) { s0[wid] = a0; s1[wid] = a1; }
    __syncthreads();
    if (t == 0) {
      double A0 = s0[0] + s0[1] + s0[2] + s0[3];
      double A1 = s1[0] + s1[1] + s1[2] + s1[3];
      double n = (double)g_ns;
      out[0] = (float)(A0 / n);
      out[1] = (float)(A1 / n);
    }
  }
}

// ---------------- launcher ----------------
extern "C" void kernel_launch(void* const* d_in, const int* in_sizes, int n_in,
                              void* d_out, int out_size, void* d_ws, size_t ws_size,
                              hipStream_t stream) {
  // setup_inputs() inserts cls/reg INTERLEAVED: cls0,reg0,cls1,reg1,...,tb,tcls
  const float* c0 = (const float*)d_in[0];
  const float* r0 = (const float*)d_in[1];
  const float* c1 = (const float*)d_in[2];
  const float* r1 = (const float*)d_in[3];
  const float* c2 = (const float*)d_in[4];
  const float* r2 = (const float*)d_in[5];
  const float* c3 = (const float*)d_in[6];
  const float* r3 = (const float*)d_in[7];
  const float* c4 = (const float*)d_in[8];
  const float* r4 = (const float*)d_in[9];
  const float* tb = (const float*)d_in[10];
  const int* tcls = (const int*)d_in[11];
  float* out = (float*)d_out;

  k_setup<<<dim3(NBLK_ANC + NB * NG), dim3(256), 0, stream>>>(tb);
  k_assign<<<dim3((KTOT + 256 * APB - 1) / (256 * APB), NB), dim3(256), 0, stream>>>(tb, tcls);
  k_loss<<<dim3(LOSS_BLOCKS), dim3(256), 0, stream>>>(c0, c1, c2, c3, c4,
                                                      r0, r1, r2, r3, r4, tb, out);
}

// Round 9
// 220.129 us; speedup vs baseline: 1.9254x; 1.9254x over previous
//
#include <hip/hip_runtime.h>
#include <cstdint>

#define DEVINL __device__ __forceinline__

// ---------------- problem geometry ----------------
constexpr int NB = 8;        // batch
constexpr int NG = 50;       // gts per image
constexpr int KTOT = 120087; // total anchors per image
constexpr int BK = NB * KTOT;

constexpr int L_W[5]   = {100, 50, 25, 13, 7};
constexpr int L_K[5]   = {90000, 22500, 5625, 1521, 441};
constexpr int L_OFF[5] = {0, 90000, 112500, 118125, 119646};
constexpr int L_WSB[5] = {0, 720000, 900000, 945000, 957168}; // L_OFF * NB

// base anchor tables (float64, matching numpy bit-for-bit)
constexpr double HR_T[3] = {0.7071067811865476, 1.0, 1.4142135623730951}; // sqrt(ratios)
constexpr double WR_T[3] = {1.0 / HR_T[0], 1.0, 1.0 / HR_T[2]};          // 1/sqrt(ratios)
constexpr double SC_T[3] = {4.0, 5.039684199579493, 6.3496042078727974}; // 4*2^(i/3)

// ---------------- device-global scratch ----------------
// METADATA LAYOUTS ARE TRANSPOSED [b][a][pix] (lw: [a][pix] u64-packed) so
// that k_loss (pix-fastest threads) reads each array stride-1 across lanes.
// Rationale: gathers whose 64 lanes span 64 distinct cache lines serialize on
// per-CU miss concurrency (~800cy per instr) — that was R8's 320us k_loss.
__device__ float4 g_anc[KTOT];
__device__ double g_accs[256][2];
__device__ unsigned g_ns;
__device__ unsigned g_done;
__device__ unsigned g_gtmax[NB * NG];
__device__ int8_t g_lab[BK];
__device__ __align__(8) int8_t g_lw[BK];
__device__ int8_t g_pos[BK];
__device__ int8_t g_mg[BK];

// ---------------- helpers ----------------
DEVINL unsigned encf(float f) { // monotonic, equality-preserving float->uint
  unsigned u = __float_as_uint(f);
  return (u & 0x80000000u) ? ~u : (u | 0x80000000u);
}
DEVINL int lvl_of(int k) {
  return (k < 90000) ? 0 : (k < 112500) ? 1 : (k < 118125) ? 2 : (k < 119646) ? 3 : 4;
}
// the ONLY IoU expression — identical instruction sequence everywhere
DEVINL float iou_one(float ax0, float ay0, float ax1, float ay1, float areaA,
                     float bx0, float by0, float bx1, float by1, float areaB) {
  float ltx = fmaxf(ax0, bx0);
  float lty = fmaxf(ay0, by0);
  float rbx = fminf(ax1, bx1);
  float rby = fminf(ay1, by1);
  float wx = fmaxf(rbx - ltx, 0.0f);
  float wy = fmaxf(rby - lty, 0.0f);
  float inter = wx * wy;
  return __fdividef(inter, areaA + areaB - inter);
}

// shared f64 anchor math: the ONE expression tree producing anchor f32 coords
DEVINL void wh_f64(int l, int a, double& wsz, double& hsz) {
  int st = 8 << l;
  int ridx = a / 3, sidx = a - ridx * 3;
  double sc = (sidx == 0) ? SC_T[0] : (sidx == 1) ? SC_T[1] : SC_T[2];
  double wr = (ridx == 0) ? WR_T[0] : (ridx == 1) ? WR_T[1] : WR_T[2];
  double hr = (ridx == 0) ? HR_T[0] : (ridx == 1) ? HR_T[1] : HR_T[2];
  wsz = wr * sc * (double)st;
  hsz = hr * sc * (double)st;
}
DEVINL void anchor_from_wh(int l, int xi, int yi, double wsz, double hsz,
                           float& x0, float& y0, float& x1, float& y1) {
  int st = 8 << l;
  double cx = (double)(xi * st), cy = (double)(yi * st);
  x0 = (float)(cx - wsz * 0.5);
  y0 = (float)(cy - hsz * 0.5);
  x1 = (float)(cx + wsz * 0.5);
  y1 = (float)(cy + hsz * 0.5);
}

// ---------------- kernel 0: setup + analytic gt_max (fused, independent) ----
constexpr int NBLK_ANC = (KTOT + 255) / 256; // 470

DEVINL int axis_cand(int xi, int i0, int lo, int hi, int Wm1) {
  int c;
  if (xi < 4) c = i0 - 1 + xi;
  else if (xi == 4) c = lo;
  else if (xi == 5) c = lo + 1;
  else if (xi == 6) c = hi - 1;
  else if (xi == 7) c = hi;
  else if (xi == 8) c = 0;
  else c = Wm1;
  return min(max(c, 0), Wm1);
}

__global__ __launch_bounds__(256) void k_setup(const float* __restrict__ tb) {
  if (blockIdx.x < NBLK_ANC) {
    if (blockIdx.x == 0) {
      int t = threadIdx.x;
      g_accs[t][0] = 0.0;
      g_accs[t][1] = 0.0;
      if (t == 0) { g_ns = 0u; g_done = 0u; }
    }
    int k = blockIdx.x * 256 + threadIdx.x;
    if (k >= KTOT) return;
    int l = lvl_of(k);
    int r = k - L_OFF[l];
    int loc = r / 9;
    int a = r - loc * 9;
    int W = L_W[l];
    int y = loc / W;
    int x = loc - y * W;
    double wsz, hsz;
    wh_f64(l, a, wsz, hsz);
    float x0, y0, x1, y1;
    anchor_from_wh(l, x, y, wsz, hsz, x0, y0, x1, y1);
    g_anc[k] = make_float4(x0, y0, x1, y1);
    return;
  }
  // analytic gtmax: candidates recompute anchors with the SAME f64 expression
  // (bit-equal to g_anc) and the SAME iou_one -> bit-identical to brute force.
  const int bg = blockIdx.x - NBLK_ANC; // b*NG + g
  float4 v = reinterpret_cast<const float4*>(tb)[bg];
  const float bx0 = v.x, by0 = v.y, bx1 = v.z, by1 = v.w;
  const float areaB = (bx1 - bx0) * (by1 - by0);
  const float bcx = 0.5f * (bx0 + bx1), bcy = 0.5f * (by0 + by1);

  float m = -1.0f;
  for (int t = threadIdx.x; t < 4500; t += 256) {
    int l = t / 900;
    int rem = t - l * 900;
    int a = rem / 100;
    int rem2 = rem - a * 100;
    int xi = rem2 / 10;
    int yi = rem2 - xi * 10;
    int W = (l == 0) ? 100 : (l == 1) ? 50 : (l == 2) ? 25 : (l == 3) ? 13 : 7;
    float stf = (float)(8 << l);
    double wsz, hsz;
    wh_f64(l, a, wsz, hsz);
    float whalf = (float)(wsz * 0.5);
    float hhalf = (float)(hsz * 0.5);
    int i0x = (int)floorf(bcx / stf);
    int lox = (int)ceilf(whalf / stf);
    int hix = (int)floorf((800.0f - whalf) / stf);
    int i0y = (int)floorf(bcy / stf);
    int loy = (int)ceilf(hhalf / stf);
    int hiy = (int)floorf((800.0f - hhalf) / stf);
    int cx = axis_cand(xi, i0x, lox, hix, W - 1);
    int cy = axis_cand(yi, i0y, loy, hiy, W - 1);
    float ax0, ay0, ax1, ay1;
    anchor_from_wh(l, cx, cy, wsz, hsz, ax0, ay0, ax1, ay1);
    bool inside = (ax0 >= 0.0f) & (ay0 >= 0.0f) & (ax1 <= 800.0f) & (ay1 <= 800.0f);
    float areaA = (ax1 - ax0) * (ay1 - ay0);
    float iou = inside ? iou_one(ax0, ay0, ax1, ay1, areaA,
                                 bx0, by0, bx1, by1, areaB)
                       : -1.0f;
    m = fmaxf(m, iou);
  }
#pragma unroll
  for (int off = 32; off; off >>= 1) m = fmaxf(m, __shfl_down(m, off));
  __shared__ float s_m[4];
  int lane = threadIdx.x & 63, wid = threadIdx.x >> 6;
  if (lane == 0) s_m[wid] = m;
  __syncthreads();
  if (threadIdx.x == 0) {
    float r = fmaxf(fmaxf(s_m[0], s_m[1]), fmaxf(s_m[2], s_m[3]));
    g_gtmax[bg] = encf(r); // sole writer, no atomic
  }
}

// ---------------- kernel 1: assignment (ballot-pruned), transposed stores ---
constexpr int APB = 4;
__global__ __launch_bounds__(256) void k_assign(const float* __restrict__ tb,
                                                const int* __restrict__ tcls) {
  const int b = blockIdx.y;
  __shared__ float s_b[NG][8]; // x0,y0,x1,y1,area,qmax
  __shared__ int s_cls[NG];
  __shared__ unsigned s_cnt;
  int tid = threadIdx.x;
  if (tid == 0) s_cnt = 0u;
  if (tid < NG) {
    float4 v = reinterpret_cast<const float4*>(tb)[b * NG + tid];
    s_b[tid][0] = v.x; s_b[tid][1] = v.y; s_b[tid][2] = v.z; s_b[tid][3] = v.w;
    s_b[tid][4] = (v.z - v.x) * (v.w - v.y);
    unsigned gm = g_gtmax[b * NG + tid];
    s_b[tid][5] = (gm > 0x80000000u) ? __uint_as_float(gm ^ 0x80000000u)
                                     : __uint_as_float(0x7FC00000u); // NaN: never ==
    s_cls[tid] = tcls[b * NG + tid];
  }
  __syncthreads();

  const int base = (blockIdx.x * 256 + tid) * APB;
  float Ax0[APB], Ay0[APB], Ax1[APB], Ay1[APB], areaA[APB];
  bool inside[APB];
  float ex0 = __builtin_inff(), ey0 = __builtin_inff();
  float ex1 = -__builtin_inff(), ey1 = -__builtin_inff();
#pragma unroll
  for (int ap = 0; ap < APB; ++ap) {
    int k = base + ap;
    bool valid = k < KTOT;
    float4 A = g_anc[valid ? k : 0];
    bool ins = valid & (A.x >= 0.0f) & (A.y >= 0.0f) & (A.z <= 800.0f) & (A.w <= 800.0f);
    inside[ap] = ins;
    ex0 = fminf(ex0, ins ? A.x : __builtin_inff());
    ey0 = fminf(ey0, ins ? A.y : __builtin_inff());
    ex1 = fmaxf(ex1, ins ? A.z : -__builtin_inff());
    ey1 = fmaxf(ey1, ins ? A.w : -__builtin_inff());
    if (!ins) A = make_float4(-4000.0f, -4000.0f, -3999.0f, -3999.0f); // IoU==0 vs any gt
    Ax0[ap] = A.x; Ay0[ap] = A.y; Ax1[ap] = A.z; Ay1[ap] = A.w;
    areaA[ap] = (A.z - A.x) * (A.w - A.y);
  }
#pragma unroll
  for (int off = 1; off < 64; off <<= 1) {
    ex0 = fminf(ex0, __shfl_xor(ex0, off));
    ey0 = fminf(ey0, __shfl_xor(ey0, off));
    ex1 = fmaxf(ex1, __shfl_xor(ex1, off));
    ey1 = fmaxf(ey1, __shfl_xor(ey1, off));
  }
  unsigned long long amask;
  {
    int g = tid & 63;
    bool act = false;
    if (g < NG) {
      float ox = fminf(ex1, s_b[g][2]) - fmaxf(ex0, s_b[g][0]);
      float oy = fminf(ey1, s_b[g][3]) - fmaxf(ey0, s_b[g][1]);
      act = (ox > 0.0f) && (oy > 0.0f);
    }
    amask = __ballot(act);
  }

  float best[APB];
  int arg[APB], lqg[APB];
#pragma unroll
  for (int ap = 0; ap < APB; ++ap) { best[ap] = -2.0f; arg[ap] = 0; lqg[ap] = -1; }

  while (amask) { // ascending g preserves first-max / last-g semantics
    int g = __builtin_ctzll(amask);
    amask &= amask - 1;
    float gx0 = s_b[g][0], gy0 = s_b[g][1], gx1 = s_b[g][2], gy1 = s_b[g][3];
    float gar = s_b[g][4], qmx = s_b[g][5];
#pragma unroll
    for (int ap = 0; ap < APB; ++ap) {
      float iou = iou_one(Ax0[ap], Ay0[ap], Ax1[ap], Ay1[ap], areaA[ap],
                          gx0, gy0, gx1, gy1, gar);
      if (iou > best[ap]) { best[ap] = iou; arg[ap] = g; }
      if (iou == qmx) lqg[ap] = g;
    }
  }

  int cnt = 0;
#pragma unroll
  for (int ap = 0; ap < APB; ++ap) {
    int k = base + ap;
    if (k < KTOT) {
      int lab = (best[ap] >= 0.5f) ? 1 : ((best[ap] >= 0.4f) ? -1 : 0);
      int mg = arg[ap];
      if (lqg[ap] >= 0) { lab = 1; mg = lqg[ap]; }
      bool pos = (lab == 1) && inside[ap];
      bool neg = (lab == 0) && inside[ap];
      int l = lvl_of(k);
      int r = k - L_OFF[l];
      int KL = (l == 0) ? 90000 : (l == 1) ? 22500 : (l == 2) ? 5625
               : (l == 3) ? 1521 : 441;
      int HWl = (l == 0) ? 10000 : (l == 1) ? 2500 : (l == 2) ? 625
                : (l == 3) ? 169 : 49;
      int WSB = (l == 0) ? 0 : (l == 1) ? 720000 : (l == 2) ? 900000
                : (l == 3) ? 945000 : 957168;
      int pix = r / 9;
      int a = r - pix * 9;
      int tIdx = WSB + b * KL + a * HWl + pix; // transposed [b][a][pix]
      g_lab[tIdx] = pos ? (int8_t)s_cls[mg] : (int8_t)0;
      g_pos[tIdx] = pos ? 1 : 0;
      g_mg[tIdx] = (int8_t)mg;
      // lw byte: flat level-local position p; consumed as W8[q=p/8][c=p%8],
      // stored u64-packed at [a(q)][pix(q)] so k_loss reads it coalesced.
      int p = b * KL + r;
      int q = p >> 3, c = p & 7;
      int pixq = q / 9;
      int aq = q - pixq * 9;
      g_lw[WSB + 8 * (aq * HWl + pixq) + c] = (pos || neg) ? 1 : 0;
      cnt += (pos || neg) ? 1 : 0;
    }
  }
#pragma unroll
  for (int off = 32; off; off >>= 1) cnt += __shfl_down(cnt, off);
  if ((tid & 63) == 0 && cnt) atomicAdd(&s_cnt, (unsigned)cnt);
  __syncthreads();
  if (tid == 0 && s_cnt) atomicAdd(&g_ns, s_cnt);
}

// ---------------- kernel 2: loss, thread-per-anchor-slot, all coalesced -----
// Thread j -> (b, a, pix) with pix fastest. Reads: lw u64 (stride-8 coalesced),
// lab/pos/mg bytes (stride-1), 8 cls planes (stride-1), reg planes pos-gated.
constexpr int S_CUM1 = 720000, S_CUM2 = 900000, S_CUM3 = 945000, S_CUM4 = 957168;
constexpr int LOSS_BLOCKS = (BK + 255) / 256; // 3753

template <int HW, int KL, int WSB, int LOFF>
DEVINL void slot_term(const float* __restrict__ cls, const float* __restrict__ reg,
                      const float4* __restrict__ tb4, int j, float& vc, float& vb) {
  int b = j / KL;
  int s = j - b * KL;
  int a = s / HW;
  int pix = s - a * HW;
  int tIdx = WSB + b * KL + a * HW + pix;

  unsigned long long lwq =
      *reinterpret_cast<const unsigned long long*>(&g_lw[WSB + 8 * (a * HW + pix)]);
  if (lwq) {
    int lab = g_lab[tIdx];
    const float* cb = cls + (b * 72 + a * 8) * HW + pix;
#pragma unroll
    for (int c = 0; c < 8; ++c) {
      float w = (float)((unsigned)(lwq >> (8 * c)) & 0xffu);
      float x = cb[c * HW];
      float t = (lab == c) ? 1.0f : 0.0f;
      float ax = fabsf(x);
      float ex = __expf(-ax);
      vc += (fmaxf(x, 0.0f) - x * t + __logf(1.0f + ex)) * w;
    }
  }
  if (g_pos[tIdx]) {
    int mg = g_mg[tIdx];
    int q = pix * 9 + a;
    float4 A = g_anc[LOFF + q];
    float aw = A.z - A.x, ah = A.w - A.y;
    float acx = A.x + 0.5f * aw, acy = A.y + 0.5f * ah;
    float4 gb = tb4[b * NG + mg];
    float gw = gb.z - gb.x, gh = gb.w - gb.y;
    float gcx = gb.x + 0.5f * gw, gcy = gb.y + 0.5f * gh;
    const float* rbase = reg + (b * 36 + a * 4) * HW + pix;
    vb += fabsf(rbase[0] - (gcx - acx) / aw);
    vb += fabsf(rbase[HW] - (gcy - acy) / ah);
    vb += fabsf(rbase[2 * HW] - logf(gw / aw));
    vb += fabsf(rbase[3 * HW] - logf(gh / ah));
  }
}

__global__ __launch_bounds__(256) void k_loss(
    const float* __restrict__ c0, const float* __restrict__ c1,
    const float* __restrict__ c2, const float* __restrict__ c3,
    const float* __restrict__ c4, const float* __restrict__ r0,
    const float* __restrict__ r1, const float* __restrict__ r2,
    const float* __restrict__ r3, const float* __restrict__ r4,
    const float* __restrict__ tb, float* __restrict__ out) {
  const float4* tb4 = reinterpret_cast<const float4*>(tb);
  int T = blockIdx.x * 256 + threadIdx.x;
  float vc = 0.0f, vb = 0.0f;
  if (T < S_CUM1)      slot_term<10000, 90000, 0, 0>(c0, r0, tb4, T, vc, vb);
  else if (T < S_CUM2) slot_term<2500, 22500, 720000, 90000>(c1, r1, tb4, T - S_CUM1, vc, vb);
  else if (T < S_CUM3) slot_term<625, 5625, 900000, 112500>(c2, r2, tb4, T - S_CUM2, vc, vb);
  else if (T < S_CUM4) slot_term<169, 1521, 945000, 118125>(c3, r3, tb4, T - S_CUM3, vc, vb);
  else if (T < BK)     slot_term<49, 441, 957168, 119646>(c4, r4, tb4, T - S_CUM4, vc, vb);

#pragma unroll
  for (int off = 32; off; off >>= 1) {
    vc += __shfl_down(vc, off);
    vb += __shfl_down(vb, off);
  }
  __shared__ float sc_[4], sb_[4];
  __shared__ bool s_last;
  int lane = threadIdx.x & 63;
  int wid = threadIdx.x >> 6;
  if (lane == 0) { sc_[wid] = vc; sb_[wid] = vb; }
  __syncthreads();
  if (threadIdx.x == 0) {
    float tc = sc_[0] + sc_[1] + sc_[2] + sc_[3];
    float tbx = sb_[0] + sb_[1] + sb_[2] + sb_[3];
    int slot = blockIdx.x & 255;
    if (tc != 0.0f) atomicAdd(&g_accs[slot][0], (double)tc);
    if (tbx != 0.0f) atomicAdd(&g_accs[slot][1], (double)tbx);
    __threadfence();
    unsigned old = atomicAdd(&g_done, 1u);
    s_last = (old == gridDim.x - 1);
  }
  __syncthreads();
  if (s_last) { // last block reduces the 256 slots and writes outputs
    int t = threadIdx.x;
    double a0 = atomicAdd(&g_accs[t][0], 0.0); // atomic read -> coherent
    double a1 = atomicAdd(&g_accs[t][1], 0.0);
#pragma unroll
    for (int off = 32; off; off >>= 1) {
      a0 += __shfl_down(a0, off);
      a1 += __shfl_down(a1, off);
    }
    __shared__ double s0[4], s1[4];
    if (lane == 0) { s0[wid] = a0; s1[wid] = a1; }
    __syncthreads();
    if (t == 0) {
      double A0 = s0[0] + s0[1] + s0[2] + s0[3];
      double A1 = s1[0] + s1[1] + s1[2] + s1[3];
      double n = (double)g_ns;
      out[0] = (float)(A0 / n);
      out[1] = (float)(A1 / n);
    }
  }
}

// ---------------- launcher ----------------
extern "C" void kernel_launch(void* const* d_in, const int* in_sizes, int n_in,
                              void* d_out, int out_size, void* d_ws, size_t ws_size,
                              hipStream_t stream) {
  // setup_inputs() inserts cls/reg INTERLEAVED: cls0,reg0,cls1,reg1,...,tb,tcls
  const float* c0 = (const float*)d_in[0];
  const float* r0 = (const float*)d_in[1];
  const float* c1 = (const float*)d_in[2];
  const float* r1 = (const float*)d_in[3];
  const float* c2 = (const float*)d_in[4];
  const float* r2 = (const float*)d_in[5];
  const float* c3 = (const float*)d_in[6];
  const float* r3 = (const float*)d_in[7];
  const float* c4 = (const float*)d_in[8];
  const float* r4 = (const float*)d_in[9];
  const float* tb = (const float*)d_in[10];
  const int* tcls = (const int*)d_in[11];
  float* out = (float*)d_out;

  k_setup<<<dim3(NBLK_ANC + NB * NG), dim3(256), 0, stream>>>(tb);
  k_assign<<<dim3((KTOT + 256 * APB - 1) / (256 * APB), NB), dim3(256), 0, stream>>>(tb, tcls);
  k_loss<<<dim3(LOSS_BLOCKS), dim3(256), 0, stream>>>(c0, c1, c2, c3, c4,
                                                      r0, r1, r2, r3, r4, tb, out);
}

// Round 10
// 165.041 us; speedup vs baseline: 2.5681x; 1.3338x over previous
//
#include <hip/hip_runtime.h>
#include <cstdint>

#define DEVINL __device__ __forceinline__

// ---------------- problem geometry ----------------
constexpr int NB = 8;        // batch
constexpr int NG = 50;       // gts per image
constexpr int KTOT = 120087; // total anchors per image
constexpr int BK = NB * KTOT;

constexpr int L_W[5]   = {100, 50, 25, 13, 7};
constexpr int L_K[5]   = {90000, 22500, 5625, 1521, 441};
constexpr int L_OFF[5] = {0, 90000, 112500, 118125, 119646};
constexpr int L_WSB[5] = {0, 720000, 900000, 945000, 957168}; // L_OFF * NB

// base anchor tables (float64, matching numpy bit-for-bit)
constexpr double HR_T[3] = {0.7071067811865476, 1.0, 1.4142135623730951}; // sqrt(ratios)
constexpr double WR_T[3] = {1.0 / HR_T[0], 1.0, 1.0 / HR_T[2]};          // 1/sqrt(ratios)
constexpr double SC_T[3] = {4.0, 5.039684199579493, 6.3496042078727974}; // 4*2^(i/3)

// ---------------- device-global scratch ----------------
// Metadata layouts are TRANSPOSED [b][a][pix] (lw: [a][pix]*8+c) so loss-side
// reads are stride-1/stride-8 across lanes (R8 lesson: 64-distinct-line
// gathers serialize on per-CU miss concurrency).
__device__ float4 g_anc[KTOT];
__device__ double g_accs[256][2];
__device__ unsigned g_ns;
__device__ unsigned g_gtmax[NB * NG];
__device__ int8_t g_lab[BK];
__device__ __align__(8) int8_t g_lw[BK];
__device__ int8_t g_pos[BK];
__device__ int8_t g_mg[BK];

// ---------------- helpers ----------------
DEVINL unsigned encf(float f) { // monotonic, equality-preserving float->uint
  unsigned u = __float_as_uint(f);
  return (u & 0x80000000u) ? ~u : (u | 0x80000000u);
}
DEVINL int lvl_of(int k) {
  return (k < 90000) ? 0 : (k < 112500) ? 1 : (k < 118125) ? 2 : (k < 119646) ? 3 : 4;
}
// the ONLY IoU expression — identical instruction sequence everywhere
DEVINL float iou_one(float ax0, float ay0, float ax1, float ay1, float areaA,
                     float bx0, float by0, float bx1, float by1, float areaB) {
  float ltx = fmaxf(ax0, bx0);
  float lty = fmaxf(ay0, by0);
  float rbx = fminf(ax1, bx1);
  float rby = fminf(ay1, by1);
  float wx = fmaxf(rbx - ltx, 0.0f);
  float wy = fmaxf(rby - lty, 0.0f);
  float inter = wx * wy;
  return __fdividef(inter, areaA + areaB - inter);
}

// shared f64 anchor math: the ONE expression tree producing anchor f32 coords
DEVINL void wh_f64(int l, int a, double& wsz, double& hsz) {
  int st = 8 << l;
  int ridx = a / 3, sidx = a - ridx * 3;
  double sc = (sidx == 0) ? SC_T[0] : (sidx == 1) ? SC_T[1] : SC_T[2];
  double wr = (ridx == 0) ? WR_T[0] : (ridx == 1) ? WR_T[1] : WR_T[2];
  double hr = (ridx == 0) ? HR_T[0] : (ridx == 1) ? HR_T[1] : HR_T[2];
  wsz = wr * sc * (double)st;
  hsz = hr * sc * (double)st;
}
DEVINL void anchor_from_wh(int l, int xi, int yi, double wsz, double hsz,
                           float& x0, float& y0, float& x1, float& y1) {
  int st = 8 << l;
  double cx = (double)(xi * st), cy = (double)(yi * st);
  x0 = (float)(cx - wsz * 0.5);
  y0 = (float)(cy - hsz * 0.5);
  x1 = (float)(cx + wsz * 0.5);
  y1 = (float)(cy + hsz * 0.5);
}

// ---------------- kernel 0: setup + analytic gt_max (fused, independent) ----
constexpr int NBLK_ANC = (KTOT + 255) / 256; // 470

DEVINL int axis_cand(int xi, int i0, int lo, int hi, int Wm1) {
  int c;
  if (xi < 4) c = i0 - 1 + xi;
  else if (xi == 4) c = lo;
  else if (xi == 5) c = lo + 1;
  else if (xi == 6) c = hi - 1;
  else if (xi == 7) c = hi;
  else if (xi == 8) c = 0;
  else c = Wm1;
  return min(max(c, 0), Wm1);
}

__global__ __launch_bounds__(256) void k_setup(const float* __restrict__ tb) {
  if (blockIdx.x < NBLK_ANC) {
    if (blockIdx.x == 0) {
      int t = threadIdx.x;
      g_accs[t][0] = 0.0;
      g_accs[t][1] = 0.0;
      if (t == 0) g_ns = 0u;
    }
    int k = blockIdx.x * 256 + threadIdx.x;
    if (k >= KTOT) return;
    int l = lvl_of(k);
    int r = k - L_OFF[l];
    int loc = r / 9;
    int a = r - loc * 9;
    int W = L_W[l];
    int y = loc / W;
    int x = loc - y * W;
    double wsz, hsz;
    wh_f64(l, a, wsz, hsz);
    float x0, y0, x1, y1;
    anchor_from_wh(l, x, y, wsz, hsz, x0, y0, x1, y1);
    g_anc[k] = make_float4(x0, y0, x1, y1);
    return;
  }
  // analytic gtmax: candidates recompute anchors with the SAME f64 expression
  // (bit-equal to g_anc) and the SAME iou_one -> bit-identical to brute force.
  const int bg = blockIdx.x - NBLK_ANC; // b*NG + g
  float4 v = reinterpret_cast<const float4*>(tb)[bg];
  const float bx0 = v.x, by0 = v.y, bx1 = v.z, by1 = v.w;
  const float areaB = (bx1 - bx0) * (by1 - by0);
  const float bcx = 0.5f * (bx0 + bx1), bcy = 0.5f * (by0 + by1);

  float m = -1.0f;
  for (int t = threadIdx.x; t < 4500; t += 256) {
    int l = t / 900;
    int rem = t - l * 900;
    int a = rem / 100;
    int rem2 = rem - a * 100;
    int xi = rem2 / 10;
    int yi = rem2 - xi * 10;
    int W = (l == 0) ? 100 : (l == 1) ? 50 : (l == 2) ? 25 : (l == 3) ? 13 : 7;
    float stf = (float)(8 << l);
    double wsz, hsz;
    wh_f64(l, a, wsz, hsz);
    float whalf = (float)(wsz * 0.5);
    float hhalf = (float)(hsz * 0.5);
    int i0x = (int)floorf(bcx / stf);
    int lox = (int)ceilf(whalf / stf);
    int hix = (int)floorf((800.0f - whalf) / stf);
    int i0y = (int)floorf(bcy / stf);
    int loy = (int)ceilf(hhalf / stf);
    int hiy = (int)floorf((800.0f - hhalf) / stf);
    int cx = axis_cand(xi, i0x, lox, hix, W - 1);
    int cy = axis_cand(yi, i0y, loy, hiy, W - 1);
    float ax0, ay0, ax1, ay1;
    anchor_from_wh(l, cx, cy, wsz, hsz, ax0, ay0, ax1, ay1);
    bool inside = (ax0 >= 0.0f) & (ay0 >= 0.0f) & (ax1 <= 800.0f) & (ay1 <= 800.0f);
    float areaA = (ax1 - ax0) * (ay1 - ay0);
    float iou = inside ? iou_one(ax0, ay0, ax1, ay1, areaA,
                                 bx0, by0, bx1, by1, areaB)
                       : -1.0f;
    m = fmaxf(m, iou);
  }
#pragma unroll
  for (int off = 32; off; off >>= 1) m = fmaxf(m, __shfl_down(m, off));
  __shared__ float s_m[4];
  int lane = threadIdx.x & 63, wid = threadIdx.x >> 6;
  if (lane == 0) s_m[wid] = m;
  __syncthreads();
  if (threadIdx.x == 0) {
    float r = fmaxf(fmaxf(s_m[0], s_m[1]), fmaxf(s_m[2], s_m[3]));
    g_gtmax[bg] = encf(r); // sole writer, no atomic
  }
}

// ---------------- kernel 1: assignment (ballot-pruned), transposed stores ---
constexpr int APB = 4;
__global__ __launch_bounds__(256) void k_assign(const float* __restrict__ tb,
                                                const int* __restrict__ tcls) {
  const int b = blockIdx.y;
  __shared__ float s_b[NG][8]; // x0,y0,x1,y1,area,qmax
  __shared__ int s_cls[NG];
  __shared__ unsigned s_cnt;
  int tid = threadIdx.x;
  if (tid == 0) s_cnt = 0u;
  if (tid < NG) {
    float4 v = reinterpret_cast<const float4*>(tb)[b * NG + tid];
    s_b[tid][0] = v.x; s_b[tid][1] = v.y; s_b[tid][2] = v.z; s_b[tid][3] = v.w;
    s_b[tid][4] = (v.z - v.x) * (v.w - v.y);
    unsigned gm = g_gtmax[b * NG + tid];
    s_b[tid][5] = (gm > 0x80000000u) ? __uint_as_float(gm ^ 0x80000000u)
                                     : __uint_as_float(0x7FC00000u); // NaN: never ==
    s_cls[tid] = tcls[b * NG + tid];
  }
  __syncthreads();

  const int base = (blockIdx.x * 256 + tid) * APB;
  float Ax0[APB], Ay0[APB], Ax1[APB], Ay1[APB], areaA[APB];
  bool inside[APB];
  float ex0 = __builtin_inff(), ey0 = __builtin_inff();
  float ex1 = -__builtin_inff(), ey1 = -__builtin_inff();
#pragma unroll
  for (int ap = 0; ap < APB; ++ap) {
    int k = base + ap;
    bool valid = k < KTOT;
    float4 A = g_anc[valid ? k : 0];
    bool ins = valid & (A.x >= 0.0f) & (A.y >= 0.0f) & (A.z <= 800.0f) & (A.w <= 800.0f);
    inside[ap] = ins;
    ex0 = fminf(ex0, ins ? A.x : __builtin_inff());
    ey0 = fminf(ey0, ins ? A.y : __builtin_inff());
    ex1 = fmaxf(ex1, ins ? A.z : -__builtin_inff());
    ey1 = fmaxf(ey1, ins ? A.w : -__builtin_inff());
    if (!ins) A = make_float4(-4000.0f, -4000.0f, -3999.0f, -3999.0f); // IoU==0 vs any gt
    Ax0[ap] = A.x; Ay0[ap] = A.y; Ax1[ap] = A.z; Ay1[ap] = A.w;
    areaA[ap] = (A.z - A.x) * (A.w - A.y);
  }
#pragma unroll
  for (int off = 1; off < 64; off <<= 1) {
    ex0 = fminf(ex0, __shfl_xor(ex0, off));
    ey0 = fminf(ey0, __shfl_xor(ey0, off));
    ex1 = fmaxf(ex1, __shfl_xor(ex1, off));
    ey1 = fmaxf(ey1, __shfl_xor(ey1, off));
  }
  unsigned long long amask;
  {
    int g = tid & 63;
    bool act = false;
    if (g < NG) {
      float ox = fminf(ex1, s_b[g][2]) - fmaxf(ex0, s_b[g][0]);
      float oy = fminf(ey1, s_b[g][3]) - fmaxf(ey0, s_b[g][1]);
      act = (ox > 0.0f) && (oy > 0.0f);
    }
    amask = __ballot(act);
  }

  float best[APB];
  int arg[APB], lqg[APB];
#pragma unroll
  for (int ap = 0; ap < APB; ++ap) { best[ap] = -2.0f; arg[ap] = 0; lqg[ap] = -1; }

  while (amask) { // ascending g preserves first-max / last-g semantics
    int g = __builtin_ctzll(amask);
    amask &= amask - 1;
    float gx0 = s_b[g][0], gy0 = s_b[g][1], gx1 = s_b[g][2], gy1 = s_b[g][3];
    float gar = s_b[g][4], qmx = s_b[g][5];
#pragma unroll
    for (int ap = 0; ap < APB; ++ap) {
      float iou = iou_one(Ax0[ap], Ay0[ap], Ax1[ap], Ay1[ap], areaA[ap],
                          gx0, gy0, gx1, gy1, gar);
      if (iou > best[ap]) { best[ap] = iou; arg[ap] = g; }
      if (iou == qmx) lqg[ap] = g;
    }
  }

  int cnt = 0;
#pragma unroll
  for (int ap = 0; ap < APB; ++ap) {
    int k = base + ap;
    if (k < KTOT) {
      int lab = (best[ap] >= 0.5f) ? 1 : ((best[ap] >= 0.4f) ? -1 : 0);
      int mg = arg[ap];
      if (lqg[ap] >= 0) { lab = 1; mg = lqg[ap]; }
      bool pos = (lab == 1) && inside[ap];
      bool neg = (lab == 0) && inside[ap];
      int l = lvl_of(k);
      int r = k - L_OFF[l];
      int KL = (l == 0) ? 90000 : (l == 1) ? 22500 : (l == 2) ? 5625
               : (l == 3) ? 1521 : 441;
      int HWl = (l == 0) ? 10000 : (l == 1) ? 2500 : (l == 2) ? 625
                : (l == 3) ? 169 : 49;
      int WSB = (l == 0) ? 0 : (l == 1) ? 720000 : (l == 2) ? 900000
                : (l == 3) ? 945000 : 957168;
      int pix = r / 9;
      int a = r - pix * 9;
      int tIdx = WSB + b * KL + a * HWl + pix; // transposed [b][a][pix]
      g_lab[tIdx] = pos ? (int8_t)s_cls[mg] : (int8_t)0;
      g_pos[tIdx] = pos ? 1 : 0;
      g_mg[tIdx] = (int8_t)mg;
      // lw byte: flat level-local position p; consumed as W8[q=p/8][c=p%8],
      // stored at [a(q)][pix(q)]*8+c so loss reads it at lane-stride 8.
      int p = b * KL + r;
      int q = p >> 3, c = p & 7;
      int pixq = q / 9;
      int aq = q - pixq * 9;
      g_lw[WSB + 8 * (aq * HWl + pixq) + c] = (pos || neg) ? 1 : 0;
      cnt += (pos || neg) ? 1 : 0;
    }
  }
#pragma unroll
  for (int off = 32; off; off >>= 1) cnt += __shfl_down(cnt, off);
  if ((tid & 63) == 0 && cnt) atomicAdd(&s_cnt, (unsigned)cnt);
  __syncthreads();
  if (tid == 0 && s_cnt) atomicAdd(&g_ns, s_cnt);
}

// ---------------- kernel 2: loss — element-per-thread, max TLP --------------
// Part C: one thread per cls element (7.69M). (b,ch,pix) pix-fastest:
//   w byte lane-stride-8, x stride-1, lab stride-1. Chain: w -> (x,lab).
// Part B: one thread per anchor-slot (960K): g_pos[T] is stride-1 by layout.
constexpr int C_OFF1 = 5760000, C_OFF2 = 7200000, C_OFF3 = 7560000, C_OFF4 = 7657344;
constexpr int C_TOT = 7685568;
constexpr int LOSS_THREADS = C_TOT + BK; // 8,646,264
constexpr int LOSS_BLOCKS = (LOSS_THREADS + 255) / 256; // 33,775

template <int HW, int KL, int WSB>
DEVINL void cls_elem(const float* __restrict__ cls, int idx, float& vc) {
  constexpr int CHW = 72 * HW;
  int b = idx / CHW;
  int r = idx - b * CHW;
  int ch = r / HW;
  int pix = r - ch * HW;
  int a = ch >> 3, c = ch & 7;
  float w = (float)g_lw[WSB + 8 * (a * HW + pix) + c];
  if (w != 0.0f) {
    float x = cls[idx];
    int lab = g_lab[WSB + b * KL + a * HW + pix];
    float t = (lab == c) ? 1.0f : 0.0f;
    float ax = fabsf(x);
    float ex = __expf(-ax);
    vc += fmaxf(x, 0.0f) - x * t + __logf(1.0f + ex);
  }
}

template <int HW, int KL, int WSB, int LOFF>
DEVINL void box_slot(const float* __restrict__ reg, const float4* __restrict__ tb4,
                     int j, float& vb) {
  if (!g_pos[WSB + j]) return;
  int b = j / KL;
  int s = j - b * KL;
  int a = s / HW;
  int pix = s - a * HW;
  int mg = g_mg[WSB + j];
  int q = pix * 9 + a;
  float4 A = g_anc[LOFF + q];
  float aw = A.z - A.x, ah = A.w - A.y;
  float acx = A.x + 0.5f * aw, acy = A.y + 0.5f * ah;
  float4 gb = tb4[b * NG + mg];
  float gw = gb.z - gb.x, gh = gb.w - gb.y;
  float gcx = gb.x + 0.5f * gw, gcy = gb.y + 0.5f * gh;
  const float* rbase = reg + (b * 36 + a * 4) * HW + pix;
  vb += fabsf(rbase[0] - (gcx - acx) / aw);
  vb += fabsf(rbase[HW] - (gcy - acy) / ah);
  vb += fabsf(rbase[2 * HW] - logf(gw / aw));
  vb += fabsf(rbase[3 * HW] - logf(gh / ah));
}

constexpr int S_CUM1 = 720000, S_CUM2 = 900000, S_CUM3 = 945000, S_CUM4 = 957168;

__global__ __launch_bounds__(256) void k_loss(
    const float* __restrict__ c0, const float* __restrict__ c1,
    const float* __restrict__ c2, const float* __restrict__ c3,
    const float* __restrict__ c4, const float* __restrict__ r0,
    const float* __restrict__ r1, const float* __restrict__ r2,
    const float* __restrict__ r3, const float* __restrict__ r4,
    const float* __restrict__ tb) {
  const float4* tb4 = reinterpret_cast<const float4*>(tb);
  int T = blockIdx.x * 256 + threadIdx.x;
  float vc = 0.0f, vb = 0.0f;
  if (T < C_TOT) {
    if (T < C_OFF1)      cls_elem<10000, 90000, 0>(c0, T, vc);
    else if (T < C_OFF2) cls_elem<2500, 22500, 720000>(c1, T - C_OFF1, vc);
    else if (T < C_OFF3) cls_elem<625, 5625, 900000>(c2, T - C_OFF2, vc);
    else if (T < C_OFF4) cls_elem<169, 1521, 945000>(c3, T - C_OFF3, vc);
    else                 cls_elem<49, 441, 957168>(c4, T - C_OFF4, vc);
  } else if (T < LOSS_THREADS) {
    int j = T - C_TOT;
    if (j < S_CUM1)      box_slot<10000, 90000, 0, 0>(r0, tb4, j, vb);
    else if (j < S_CUM2) box_slot<2500, 22500, 720000, 90000>(r1, tb4, j - S_CUM1, vb);
    else if (j < S_CUM3) box_slot<625, 5625, 900000, 112500>(r2, tb4, j - S_CUM2, vb);
    else if (j < S_CUM4) box_slot<169, 1521, 945000, 118125>(r3, tb4, j - S_CUM3, vb);
    else                 box_slot<49, 441, 957168, 119646>(r4, tb4, j - S_CUM4, vb);
  }
#pragma unroll
  for (int off = 32; off; off >>= 1) {
    vc += __shfl_down(vc, off);
    vb += __shfl_down(vb, off);
  }
  __shared__ float sc_[4], sb_[4];
  int lane = threadIdx.x & 63;
  int wid = threadIdx.x >> 6;
  if (lane == 0) { sc_[wid] = vc; sb_[wid] = vb; }
  __syncthreads();
  if (threadIdx.x == 0) {
    float tc = sc_[0] + sc_[1] + sc_[2] + sc_[3];
    float tbx = sb_[0] + sb_[1] + sb_[2] + sb_[3];
    int slot = blockIdx.x & 255;
    if (tc != 0.0f) atomicAdd(&g_accs[slot][0], (double)tc);
    if (tbx != 0.0f) atomicAdd(&g_accs[slot][1], (double)tbx);
  }
}

// ---------------- kernel 3: finalize (separate launch; no fences) -----------
__global__ __launch_bounds__(256) void k_fin(float* __restrict__ out) {
  int t = threadIdx.x;
  double a0 = g_accs[t][0];
  double a1 = g_accs[t][1];
#pragma unroll
  for (int off = 32; off; off >>= 1) {
    a0 += __shfl_down(a0, off);
    a1 += __shfl_down(a1, off);
  }
  __shared__ double s0[4], s1[4];
  if ((t & 63) == 0) { s0[t >> 6] = a0; s1[t >> 6] = a1; }
  __syncthreads();
  if (t == 0) {
    double A0 = s0[0] + s0[1] + s0[2] + s0[3];
    double A1 = s1[0] + s1[1] + s1[2] + s1[3];
    double n = (double)g_ns;
    out[0] = (float)(A0 / n);
    out[1] = (float)(A1 / n);
  }
}

// ---------------- launcher ----------------
extern "C" void kernel_launch(void* const* d_in, const int* in_sizes, int n_in,
                              void* d_out, int out_size, void* d_ws, size_t ws_size,
                              hipStream_t stream) {
  // setup_inputs() inserts cls/reg INTERLEAVED: cls0,reg0,cls1,reg1,...,tb,tcls
  const float* c0 = (const float*)d_in[0];
  const float* r0 = (const float*)d_in[1];
  const float* c1 = (const float*)d_in[2];
  const float* r1 = (const float*)d_in[3];
  const float* c2 = (const float*)d_in[4];
  const float* r2 = (const float*)d_in[5];
  const float* c3 = (const float*)d_in[6];
  const float* r3 = (const float*)d_in[7];
  const float* c4 = (const float*)d_in[8];
  const float* r4 = (const float*)d_in[9];
  const float* tb = (const float*)d_in[10];
  const int* tcls = (const int*)d_in[11];
  float* out = (float*)d_out;

  k_setup<<<dim3(NBLK_ANC + NB * NG), dim3(256), 0, stream>>>(tb);
  k_assign<<<dim3((KTOT + 256 * APB - 1) / (256 * APB), NB), dim3(256), 0, stream>>>(tb, tcls);
  k_loss<<<dim3(LOSS_BLOCKS), dim3(256), 0, stream>>>(c0, c1, c2, c3, c4,
                                                      r0, r1, r2, r3, r4, tb);
  k_fin<<<dim3(1), dim3(256), 0, stream>>>(out);
}